// Round 4
// baseline (540.476 us; speedup 1.0000x reference)
//
#include <hip/hip_runtime.h>
#include <math.h>

#define S_LEN 2048
#define D_MODEL 4096
#define NH 32
#define NKV 4
#define HD 128
#define KV_W (NKV * HD)        // 512
#define QK_W (D_MODEL + KV_W)  // 4608
#define QKV_W (QK_W + KV_W)    // 5120 fused q+k+v projection width

typedef float f32x4 __attribute__((ext_vector_type(4)));
typedef __bf16 bf16x8 __attribute__((ext_vector_type(8)));

// async global->LDS 16B copy. LDS dest = wave-uniform base + lane*16.
__device__ __forceinline__ void async16(const __bf16* g, __bf16* l) {
    __builtin_amdgcn_global_load_lds(
        (const __attribute__((address_space(1))) unsigned int*)g,
        (__attribute__((address_space(3))) unsigned int*)l, 16, 0, 0);
}

// ---------------- cast fp32 -> bf16 ----------------
__global__ void cast_f32_bf16(const float* __restrict__ in, __bf16* __restrict__ out, int n) {
    int i = (blockIdx.x * blockDim.x + threadIdx.x) * 4;
    if (i >= n) return;
    float4 v = *reinterpret_cast<const float4*>(in + i);
    out[i + 0] = (__bf16)v.x;
    out[i + 1] = (__bf16)v.y;
    out[i + 2] = (__bf16)v.z;
    out[i + 3] = (__bf16)v.w;
}

// ---------------- transpose + cast: in[R][C] f32 -> out[C][R] bf16 ----------------
__global__ void transpose_cast(const float* __restrict__ in, __bf16* __restrict__ out, int R, int C) {
    __shared__ float tile[64][65];
    const int tid = threadIdx.x;
    const int bx = blockIdx.x * 64, by = blockIdx.y * 64;
#pragma unroll
    for (int i = 0; i < 4; i++) {
        int idx = tid + i * 256;          // 0..1023
        int r = idx >> 4, c4 = (idx & 15) * 4;
        float4 v = *(const float4*)(in + (size_t)(by + r) * C + bx + c4);
        tile[r][c4 + 0] = v.x; tile[r][c4 + 1] = v.y;
        tile[r][c4 + 2] = v.z; tile[r][c4 + 3] = v.w;
    }
    __syncthreads();
#pragma unroll
    for (int i = 0; i < 2; i++) {
        int idx = tid + i * 256;          // 0..511
        int oc = idx >> 3, r8 = (idx & 7) * 8;  // out-row bx+oc, elems by+r8..+7
        bf16x8 v;
#pragma unroll
        for (int e = 0; e < 8; e++) v[e] = (__bf16)tile[r8 + e][oc];
        *(bf16x8*)(out + (size_t)(bx + oc) * R + by + r8) = v;
    }
}

// ---------------- pipelined bf16 MFMA GEMM: C = A[M][K] * Bt[N][K]^T ----------------
// 128^2 tile, one __syncthreads per K-step, measured-best structure at this
// shape. Throughput scales with resident blocks/CU (TLP covers the barrier
// drain): 2/CU=560 TF, 2.5/CU=700 TF, 4/CU=912 TF (m103). Hence MODE 2 below.
// MODE 0: f32 [M][N] to Cp.
// MODE 1: fused QKV epilogue: n<4608 -> bf16 [M][4608] at Cp; n>=4608 -> bf16
//         transposed [n-4608][M] at Cp2 (V^T for flash).
// MODE 2: split-K=2 (blockIdx.z = K-half) with f32 atomicAdd epilogue into Cp
//         (requires Cp zero-initialized). Doubles the grid -> 4 blocks/CU.
template <int MODE>
__global__ __launch_bounds__(256, 2) void gemm_bf16(const __bf16* __restrict__ A,
                                                    const __bf16* __restrict__ Bt,
                                                    void* __restrict__ Cp, void* __restrict__ Cp2,
                                                    int M, int N, int K) {
    __shared__ __bf16 a_lds[2][128 * 32];
    __shared__ __bf16 b_lds[2][128 * 32];

    const int tid = threadIdx.x;
    const int wave = tid >> 6, lane = tid & 63;
    const int quad = lane >> 4, l16 = lane & 15;
    const int wm = wave & 1, wn = wave >> 1;
    const int m0 = blockIdx.y * 128, n0 = blockIdx.x * 128;

    // split-K: this block covers K-range [kOff, kOff+KL)
    const int KL = (MODE == 2) ? (K >> 1) : K;
    const int kOff = (MODE == 2) ? blockIdx.z * KL : 0;

    f32x4 acc[4][4];
#pragma unroll
    for (int i = 0; i < 4; i++)
#pragma unroll
        for (int j = 0; j < 4; j++) acc[i][j] = (f32x4)0.0f;

    const int crow = tid >> 2, ccol = (tid & 3) * 8;
    const __bf16* Ap0 = A + (size_t)(m0 + crow) * K + kOff + ccol;
    const __bf16* Ap1 = A + (size_t)(m0 + 64 + crow) * K + kOff + ccol;
    const __bf16* Bp0 = Bt + (size_t)(n0 + crow) * K + kOff + ccol;
    const __bf16* Bp1 = Bt + (size_t)(n0 + 64 + crow) * K + kOff + ccol;

    // prestage k-tile 0 into buffer 0
    async16(Ap0, a_lds[0] + tid * 8);
    async16(Ap1, a_lds[0] + (tid + 256) * 8);
    async16(Bp0, b_lds[0] + tid * 8);
    async16(Bp1, b_lds[0] + (tid + 256) * 8);

    for (int k0 = 0; k0 < KL; k0 += 32) {
        const int cur = (k0 >> 5) & 1;
        __syncthreads();   // publishes buf[cur]; all reads of buf[cur^1] are done
        if (k0 + 32 < KL) {
            async16(Ap0 + k0 + 32, a_lds[cur ^ 1] + tid * 8);
            async16(Ap1 + k0 + 32, a_lds[cur ^ 1] + (tid + 256) * 8);
            async16(Bp0 + k0 + 32, b_lds[cur ^ 1] + tid * 8);
            async16(Bp1 + k0 + 32, b_lds[cur ^ 1] + (tid + 256) * 8);
        }

        bf16x8 afr[4], bfr[4];
#pragma unroll
        for (int i = 0; i < 4; i++)
            afr[i] = *(const bf16x8*)(a_lds[cur] + (wm * 64 + i * 16 + l16) * 32 + quad * 8);
#pragma unroll
        for (int j = 0; j < 4; j++)
            bfr[j] = *(const bf16x8*)(b_lds[cur] + (wn * 64 + j * 16 + l16) * 32 + quad * 8);
#pragma unroll
        for (int i = 0; i < 4; i++)
#pragma unroll
            for (int j = 0; j < 4; j++)
                acc[i][j] = __builtin_amdgcn_mfma_f32_16x16x32_bf16(afr[i], bfr[j], acc[i][j], 0, 0, 0);
    }

    const bool vregion = (MODE == 1) && (n0 >= QK_W);
#pragma unroll
    for (int i = 0; i < 4; i++)
#pragma unroll
        for (int j = 0; j < 4; j++)
#pragma unroll
            for (int r = 0; r < 4; r++) {
                int gm = m0 + wm * 64 + i * 16 + quad * 4 + r;
                int gn = n0 + wn * 64 + j * 16 + l16;
                float v = acc[i][j][r];
                if constexpr (MODE == 0) {
                    ((float*)Cp)[(size_t)gm * N + gn] = v;
                } else if constexpr (MODE == 2) {
                    atomicAdd(&((float*)Cp)[(size_t)gm * N + gn], v);
                } else {
                    if (vregion)
                        ((__bf16*)Cp2)[(size_t)(gn - QK_W) * M + gm] = (__bf16)v;
                    else
                        ((__bf16*)Cp)[(size_t)gm * QK_W + gn] = (__bf16)v;
                }
            }
}

// ---------------- YaRN RoPE (bf16 strided src, bf16 out) ----------------
__global__ void rope_cast(const __bf16* __restrict__ src, int sPitch, int sOff,
                          __bf16* __restrict__ dst, int dPitch, int H, int total) {
    int idx = blockIdx.x * blockDim.x + threadIdx.x;
    if (idx >= total) return;
    int d = idx & 63;
    int t = idx >> 6;
    int h = t % H;
    int s = t / H;

    float inv = __powf(10000.0f, -(float)d * (1.0f / 64.0f));
    float wl = 6.2831853071795864f / inv;
    float r = 163840.0f / wl;
    float gamma = fminf(fmaxf((r - 1.0f) * (1.0f / 31.0f), 0.0f), 1.0f);
    float adj = inv * ((1.0f - gamma) * (1.0f / 80.0f) + gamma);
    float ang = ((float)s * adj) / 1.1992508365439246f; // / sqrt(0.1*ln(80)+1)
    float c = cosf(ang), sn = sinf(ang);

    const __bf16* b = src + (size_t)s * sPitch + sOff + h * HD;
    __bf16* o = dst + (size_t)s * dPitch + h * HD;
    float x1 = (float)b[d], x2 = (float)b[d + 64];
    o[d] = (__bf16)(x1 * c - x2 * sn);
    o[d + 64] = (__bf16)(x2 * c + x1 * sn);
}

// ---------------- flash attention v4 (pipelined, causal, GQA, fixed-max softmax) ----------------
// grid (NH, 16): t = ty<8 ? ty : 23-ty (complementary causal walls per CU).
// 4 waves x 32 q-rows (128-row q-tile), 64-key k-tiles, nk = 2t+2.
// Pipeline per iter: stage V(kt) -> QK(kt)+softmax -> barrier (drains V) ->
// stage K(kt+1) -> PV(kt) -> barrier (drains K). Every async batch gets a full
// MFMA phase of latency cover before its drain. (v5 single-barrier variant
// measured ~15 us WORSE -- reverted.)
__global__ __launch_bounds__(256, 2) void flash_attn(const __bf16* __restrict__ Q,
                                                     const __bf16* __restrict__ Kb,
                                                     const __bf16* __restrict__ Vt,
                                                     __bf16* __restrict__ O) {
    __shared__ __bf16 k_lds[2][64 * 128];  // [key][dim], XOR-swizzled chunks, double-buffered
    __shared__ __bf16 vt_lds[128 * 64];    // [dim][key], XOR-swizzled chunks
    __shared__ __bf16 p_lds[128 * 72];     // P C-layout -> A-layout round trip

    const int tid = threadIdx.x;
    const int wave = tid >> 6, lane = tid & 63;
    const int quad = lane >> 4, l16 = lane & 15;
    const int h = blockIdx.x;
    const int ty = blockIdx.y;
    const int t = (ty < 8) ? ty : 23 - ty;
    const int qb0 = t * 128;
    const int wrow = wave * 32;
    const int kvh = h >> 3;
    const float sl2e = 0.12752039149672056f;  // (1/sqrt(128)) * log2(e)

    // Q fragments in registers (A-layout), loaded once
    bf16x8 qfr[2][4];
#pragma unroll
    for (int mi = 0; mi < 2; mi++)
#pragma unroll
        for (int kk = 0; kk < 4; kk++)
            qfr[mi][kk] = *(const bf16x8*)(Q + (size_t)(qb0 + wrow + mi * 16 + l16) * D_MODEL
                                           + h * HD + kk * 32 + quad * 8);

    f32x4 acc[2][8];
#pragma unroll
    for (int mi = 0; mi < 2; mi++)
#pragma unroll
        for (int dt = 0; dt < 8; dt++) acc[mi][dt] = (f32x4)0.0f;
    float rs[2][4] = {{0.f, 0.f, 0.f, 0.f}, {0.f, 0.f, 0.f, 0.f}};

    const int nk = 2 * t + 2;

    // prestage K(0) into k_lds[0]
#pragma unroll
    for (int it = 0; it < 4; it++) {
        int c = tid + it * 256;
        int krow = c >> 4, kcb = c & 15;
        async16(Kb + (size_t)krow * KV_W + kvh * HD + ((kcb ^ (krow & 15)) << 3),
                k_lds[0] + c * 8);
    }
    __syncthreads();   // publish K(0)

    for (int kt = 0; kt < nk; kt++) {
        const int k0 = kt * 64;
        const int cur = kt & 1;

        // stage V(kt) (overlaps QK compute below; vbuf reads from iter kt-1
        // completed before the previous iteration's second barrier)
#pragma unroll
        for (int it = 0; it < 4; it++) {
            int c = tid + it * 256;
            int vrow = c >> 3, vcb = c & 7;
            async16(Vt + (size_t)(kvh * HD + vrow) * S_LEN + k0 + ((vcb ^ (vrow & 7)) << 3),
                    vt_lds + c * 8);
        }

        // ---- S = Q K^T from k_lds[cur] ----
        f32x4 sc[2][4];
#pragma unroll
        for (int mi = 0; mi < 2; mi++)
#pragma unroll
            for (int j = 0; j < 4; j++) sc[mi][j] = (f32x4)0.0f;
#pragma unroll
        for (int j = 0; j < 4; j++)
#pragma unroll
            for (int kk = 0; kk < 4; kk++) {
                bf16x8 kf = *(const bf16x8*)(k_lds[cur] + (((j * 16 + l16) << 4) + ((kk * 4 + quad) ^ l16)) * 8);
                sc[0][j] = __builtin_amdgcn_mfma_f32_16x16x32_bf16(qfr[0][kk], kf, sc[0][j], 0, 0, 0);
                sc[1][j] = __builtin_amdgcn_mfma_f32_16x16x32_bf16(qfr[1][kk], kf, sc[1][j], 0, 0, 0);
            }

        // ---- fixed-max softmax: p = exp2(s*scale*log2e), masked -> 0 ----
        const bool hasmask = (kt >= 2 * t);
#pragma unroll
        for (int mi = 0; mi < 2; mi++) {
            int rowb = qb0 + wrow + mi * 16 + quad * 4;
#pragma unroll
            for (int j = 0; j < 4; j++) {
                int kg = k0 + j * 16 + l16;
#pragma unroll
                for (int r = 0; r < 4; r++) {
                    float p = __builtin_amdgcn_exp2f(sc[mi][j][r] * sl2e);
                    if (hasmask && kg > rowb + r) p = 0.0f;
                    rs[mi][r] += p;
                    p_lds[(wrow + mi * 16 + quad * 4 + r) * 72 + j * 16 + l16] = (__bf16)p;
                }
            }
        }

        __syncthreads();   // drains V(kt) (cover: QK phase); all QK reads of k_lds[cur] done

        // stage K(kt+1) into the other buffer (overlaps PV compute; k_lds[cur^1]
        // reads finished at iter kt-1 before a barrier)
        if (kt + 1 < nk) {
#pragma unroll
            for (int it = 0; it < 4; it++) {
                int c = tid + it * 256;
                int krow = c >> 4, kcb = c & 15;
                async16(Kb + (size_t)(k0 + 64 + krow) * KV_W + kvh * HD + ((kcb ^ (krow & 15)) << 3),
                        k_lds[cur ^ 1] + c * 8);
            }
        }

        // ---- O += P V (p_lds rows wave-private; lgkmcnt orders within wave) ----
        bf16x8 pf[2][2];
#pragma unroll
        for (int mi = 0; mi < 2; mi++)
#pragma unroll
            for (int kk = 0; kk < 2; kk++)
                pf[mi][kk] = *(const bf16x8*)(p_lds + (wrow + mi * 16 + l16) * 72 + kk * 32 + quad * 8);
#pragma unroll
        for (int dt = 0; dt < 8; dt++)
#pragma unroll
            for (int kk = 0; kk < 2; kk++) {
                bf16x8 vf = *(const bf16x8*)(vt_lds + (((dt * 16 + l16) << 3) + ((kk * 4 + quad) ^ (l16 & 7))) * 8);
                acc[0][dt] = __builtin_amdgcn_mfma_f32_16x16x32_bf16(pf[0][kk], vf, acc[0][dt], 0, 0, 0);
                acc[1][dt] = __builtin_amdgcn_mfma_f32_16x16x32_bf16(pf[1][kk], vf, acc[1][dt], 0, 0, 0);
            }

        __syncthreads();   // drains K(kt+1) (cover: PV phase); PV reads of vt_lds done
    }

    // ---- final row-sum reduction across l16 (once per block) ----
    float inv_l[2][4];
#pragma unroll
    for (int mi = 0; mi < 2; mi++)
#pragma unroll
        for (int r = 0; r < 4; r++) {
            float s = rs[mi][r];
#pragma unroll
            for (int m = 1; m <= 8; m <<= 1) s += __shfl_xor(s, m, 64);
            inv_l[mi][r] = 1.0f / s;
        }

#pragma unroll
    for (int mi = 0; mi < 2; mi++)
#pragma unroll
        for (int dt = 0; dt < 8; dt++)
#pragma unroll
            for (int r = 0; r < 4; r++) {
                int row = qb0 + wrow + mi * 16 + quad * 4 + r;
                int col = h * HD + dt * 16 + l16;
                O[(size_t)row * D_MODEL + col] = (__bf16)(acc[mi][dt][r] * inv_l[mi][r]);
            }
}

// ---------------- host launch ----------------
extern "C" void kernel_launch(void* const* d_in, const int* in_sizes, int n_in,
                              void* d_out, int out_size, void* d_ws, size_t ws_size,
                              hipStream_t stream) {
    const float* x = (const float*)d_in[0];
    const float* wq = (const float*)d_in[1];
    const float* wk = (const float*)d_in[2];
    const float* wv = (const float*)d_in[3];
    const float* wo = (const float*)d_in[4];
    float* out = (float*)d_out;

    char* ws = (char*)d_ws;
    size_t off = 0;
    auto alloc = [&](size_t bytes) {
        void* p = ws + off;
        off += (bytes + 255) & ~(size_t)255;
        return p;
    };
    __bf16* xb    = (__bf16*)alloc((size_t)S_LEN * D_MODEL * 2);
    __bf16* wqkvT = (__bf16*)alloc((size_t)QKV_W * D_MODEL * 2);  // [wq^T; wk^T; wv^T]
    __bf16* woT   = (__bf16*)alloc((size_t)D_MODEL * D_MODEL * 2);
    __bf16* qkb   = (__bf16*)alloc((size_t)S_LEN * QK_W * 2);     // pre-rope q|k
    __bf16* vtb   = (__bf16*)alloc((size_t)KV_W * S_LEN * 2);     // V^T
    __bf16* qb    = (__bf16*)alloc((size_t)S_LEN * D_MODEL * 2);  // post-rope Q
    __bf16* kb    = (__bf16*)alloc((size_t)S_LEN * KV_W * 2);     // post-rope K
    __bf16* ob    = (__bf16*)alloc((size_t)S_LEN * D_MODEL * 2);  // attention out

    // 0. zero d_out for the split-K atomic epilogue
    hipMemsetAsync(out, 0, (size_t)S_LEN * D_MODEL * sizeof(float), stream);

    // 1. casts / transposes
    cast_f32_bf16<<<(S_LEN * D_MODEL) / (256 * 4), 256, 0, stream>>>(x, xb, S_LEN * D_MODEL);
    transpose_cast<<<dim3(D_MODEL / 64, D_MODEL / 64), 256, 0, stream>>>(wq, wqkvT, D_MODEL, D_MODEL);
    transpose_cast<<<dim3(KV_W / 64, D_MODEL / 64), 256, 0, stream>>>(wk, wqkvT + (size_t)D_MODEL * D_MODEL, D_MODEL, KV_W);
    transpose_cast<<<dim3(KV_W / 64, D_MODEL / 64), 256, 0, stream>>>(wv, wqkvT + (size_t)QK_W * D_MODEL, D_MODEL, KV_W);
    transpose_cast<<<dim3(D_MODEL / 64, D_MODEL / 64), 256, 0, stream>>>(wo, woT, D_MODEL, D_MODEL);

    // 2. fused Q+K+V projection (bf16 out; V written transposed) -- 640 blocks, 2.5/CU
    gemm_bf16<1><<<dim3(QKV_W / 128, S_LEN / 128), 256, 0, stream>>>(xb, wqkvT, qkb, vtb, S_LEN, QKV_W, D_MODEL);

    // 3. RoPE
    rope_cast<<<(S_LEN * NH * 64) / 256, 256, 0, stream>>>(qkb, QK_W, 0, qb, D_MODEL, NH, S_LEN * NH * 64);
    rope_cast<<<(S_LEN * NKV * 64) / 256, 256, 0, stream>>>(qkb, QK_W, D_MODEL, kb, KV_W, NKV, S_LEN * NKV * 64);

    // 4. attention (512 blocks, 2/CU, complementary-tile swizzle)
    flash_attn<<<dim3(NH, 16), 256, 0, stream>>>(qb, kb, vtb, ob);

    // 5. output projection, split-K=2 atomic f32 -> d_out -- 1024 blocks, 4/CU
    gemm_bf16<2><<<dim3(D_MODEL / 128, S_LEN / 128, 2), 256, 0, stream>>>(ob, woT, out, nullptr, S_LEN, D_MODEL, D_MODEL);
}

// Round 5
// 505.450 us; speedup vs baseline: 1.0693x; 1.0693x over previous
//
#include <hip/hip_runtime.h>
#include <math.h>

#define S_LEN 2048
#define D_MODEL 4096
#define NH 32
#define NKV 4
#define HD 128
#define KV_W (NKV * HD)        // 512
#define QK_W (D_MODEL + KV_W)  // 4608
#define QKV_W (QK_W + KV_W)    // 5120 fused q+k+v projection width

typedef float f32x4 __attribute__((ext_vector_type(4)));
typedef __bf16 bf16x8 __attribute__((ext_vector_type(8)));

// async global->LDS 16B copy. LDS dest = wave-uniform base + lane*16.
__device__ __forceinline__ void async16(const __bf16* g, __bf16* l) {
    __builtin_amdgcn_global_load_lds(
        (const __attribute__((address_space(1))) unsigned int*)g,
        (__attribute__((address_space(3))) unsigned int*)l, 16, 0, 0);
}

// ---------------- cast fp32 -> bf16 ----------------
__global__ void cast_f32_bf16(const float* __restrict__ in, __bf16* __restrict__ out, int n) {
    int i = (blockIdx.x * blockDim.x + threadIdx.x) * 4;
    if (i >= n) return;
    float4 v = *reinterpret_cast<const float4*>(in + i);
    out[i + 0] = (__bf16)v.x;
    out[i + 1] = (__bf16)v.y;
    out[i + 2] = (__bf16)v.z;
    out[i + 3] = (__bf16)v.w;
}

// ---------------- transpose + cast: in[R][C] f32 -> out[C][R] bf16 ----------------
__global__ void transpose_cast(const float* __restrict__ in, __bf16* __restrict__ out, int R, int C) {
    __shared__ float tile[64][65];
    const int tid = threadIdx.x;
    const int bx = blockIdx.x * 64, by = blockIdx.y * 64;
#pragma unroll
    for (int i = 0; i < 4; i++) {
        int idx = tid + i * 256;          // 0..1023
        int r = idx >> 4, c4 = (idx & 15) * 4;
        float4 v = *(const float4*)(in + (size_t)(by + r) * C + bx + c4);
        tile[r][c4 + 0] = v.x; tile[r][c4 + 1] = v.y;
        tile[r][c4 + 2] = v.z; tile[r][c4 + 3] = v.w;
    }
    __syncthreads();
#pragma unroll
    for (int i = 0; i < 2; i++) {
        int idx = tid + i * 256;          // 0..511
        int oc = idx >> 3, r8 = (idx & 7) * 8;  // out-row bx+oc, elems by+r8..+7
        bf16x8 v;
#pragma unroll
        for (int e = 0; e < 8; e++) v[e] = (__bf16)tile[r8 + e][oc];
        *(bf16x8*)(out + (size_t)(bx + oc) * R + by + r8) = v;
    }
}

// ---------------- pipelined bf16 MFMA GEMM: C = A[M][K] * Bt[N][K]^T ----------------
// 128^2 tile. v2: TRIPLE-buffered LDS, prefetch depth 2, counted vmcnt.
// Rationale: the old 2-buffer loop drained vmcnt(0) at each __syncthreads with
// only ONE compute phase (~300cy) of cover over the staging loads -- enough for
// L2 hits (~200cy) but not HBM misses (~900cy). At these shapes (M=2048, B-panel
// reuse 16x, FETCH=1.5x compulsory) many loads miss L2; every miss stalled all
// waves. Split-K/occupancy test (r4) falsified the TLP explanation. Depth-2
// prefetch gives each staging batch ~2 compute phases + a barrier (~800+cy) of
// cover; steady-state wait is vmcnt(4) (retire tile g+1, leave g+2 in flight) --
// never a full drain. Buffer rotation: stage (g+2)%3 at iter g; that buffer was
// last read at iter g-1, barrier-separated -> race-free.
// MODE 0: f32 [M][N] to Cp.
// MODE 1: fused QKV epilogue: n<4608 -> bf16 [M][4608] at Cp; n>=4608 -> bf16
//         transposed [n-4608][M] at Cp2 (V^T for flash).
template <int MODE>
__global__ __launch_bounds__(256, 2) void gemm_bf16(const __bf16* __restrict__ A,
                                                    const __bf16* __restrict__ Bt,
                                                    void* __restrict__ Cp, void* __restrict__ Cp2,
                                                    int M, int N, int K) {
    __shared__ __bf16 a_lds[3][128 * 32];
    __shared__ __bf16 b_lds[3][128 * 32];

    const int tid = threadIdx.x;
    const int wave = tid >> 6, lane = tid & 63;
    const int quad = lane >> 4, l16 = lane & 15;
    const int wm = wave & 1, wn = wave >> 1;
    const int m0 = blockIdx.y * 128, n0 = blockIdx.x * 128;

    f32x4 acc[4][4];
#pragma unroll
    for (int i = 0; i < 4; i++)
#pragma unroll
        for (int j = 0; j < 4; j++) acc[i][j] = (f32x4)0.0f;

    const int crow = tid >> 2, ccol = (tid & 3) * 8;
    const __bf16* Ap0 = A + (size_t)(m0 + crow) * K + ccol;
    const __bf16* Ap1 = A + (size_t)(m0 + 64 + crow) * K + ccol;
    const __bf16* Bp0 = Bt + (size_t)(n0 + crow) * K + ccol;
    const __bf16* Bp1 = Bt + (size_t)(n0 + 64 + crow) * K + ccol;

    auto stage = [&](int buf, int k0s) {
        async16(Ap0 + k0s, a_lds[buf] + tid * 8);
        async16(Ap1 + k0s, a_lds[buf] + (tid + 256) * 8);
        async16(Bp0 + k0s, b_lds[buf] + tid * 8);
        async16(Bp1 + k0s, b_lds[buf] + (tid + 256) * 8);
    };

    // prologue: stage k-tiles 0,1; retire tile 0 (vmcnt(4) leaves tile 1 in flight)
    stage(0, 0);
    stage(1, 32);
    asm volatile("s_waitcnt vmcnt(4)" ::: "memory");
    __builtin_amdgcn_sched_barrier(0);
    __builtin_amdgcn_s_barrier();

    int cur = 0;
    for (int k0 = 0; k0 < K; k0 += 32) {
        // stage k-tile g+2 into buffer (cur+2)%3 (last read at iter g-1, barrier-separated)
        int nx2 = cur + 2; if (nx2 >= 3) nx2 -= 3;
        if (k0 + 64 < K) stage(nx2, k0 + 64);

        bf16x8 afr[4], bfr[4];
#pragma unroll
        for (int i = 0; i < 4; i++)
            afr[i] = *(const bf16x8*)(a_lds[cur] + (wm * 64 + i * 16 + l16) * 32 + quad * 8);
#pragma unroll
        for (int j = 0; j < 4; j++)
            bfr[j] = *(const bf16x8*)(b_lds[cur] + (wn * 64 + j * 16 + l16) * 32 + quad * 8);
#pragma unroll
        for (int i = 0; i < 4; i++)
#pragma unroll
            for (int j = 0; j < 4; j++)
                acc[i][j] = __builtin_amdgcn_mfma_f32_16x16x32_bf16(afr[i], bfr[j], acc[i][j], 0, 0, 0);

        // end-of-iter: retire tile g+1's 4 loads (issued at iter g-1, ~full
        // iteration of latency cover); leave tile g+2's 4 in flight.
        if (k0 + 32 < K) {
            if (k0 + 64 < K) { asm volatile("s_waitcnt vmcnt(4)" ::: "memory"); }
            else             { asm volatile("s_waitcnt vmcnt(0)" ::: "memory"); }
            __builtin_amdgcn_sched_barrier(0);
            __builtin_amdgcn_s_barrier();
        }

        cur++; if (cur >= 3) cur -= 3;
    }

    const bool vregion = (MODE == 1) && (n0 >= QK_W);
#pragma unroll
    for (int i = 0; i < 4; i++)
#pragma unroll
        for (int j = 0; j < 4; j++)
#pragma unroll
            for (int r = 0; r < 4; r++) {
                int gm = m0 + wm * 64 + i * 16 + quad * 4 + r;
                int gn = n0 + wn * 64 + j * 16 + l16;
                float v = acc[i][j][r];
                if constexpr (MODE == 0) {
                    ((float*)Cp)[(size_t)gm * N + gn] = v;
                } else {
                    if (vregion)
                        ((__bf16*)Cp2)[(size_t)(gn - QK_W) * M + gm] = (__bf16)v;
                    else
                        ((__bf16*)Cp)[(size_t)gm * QK_W + gn] = (__bf16)v;
                }
            }
}

// ---------------- YaRN RoPE (bf16 strided src, bf16 out) ----------------
__global__ void rope_cast(const __bf16* __restrict__ src, int sPitch, int sOff,
                          __bf16* __restrict__ dst, int dPitch, int H, int total) {
    int idx = blockIdx.x * blockDim.x + threadIdx.x;
    if (idx >= total) return;
    int d = idx & 63;
    int t = idx >> 6;
    int h = t % H;
    int s = t / H;

    float inv = __powf(10000.0f, -(float)d * (1.0f / 64.0f));
    float wl = 6.2831853071795864f / inv;
    float r = 163840.0f / wl;
    float gamma = fminf(fmaxf((r - 1.0f) * (1.0f / 31.0f), 0.0f), 1.0f);
    float adj = inv * ((1.0f - gamma) * (1.0f / 80.0f) + gamma);
    float ang = ((float)s * adj) / 1.1992508365439246f; // / sqrt(0.1*ln(80)+1)
    float c = cosf(ang), sn = sinf(ang);

    const __bf16* b = src + (size_t)s * sPitch + sOff + h * HD;
    __bf16* o = dst + (size_t)s * dPitch + h * HD;
    float x1 = (float)b[d], x2 = (float)b[d + 64];
    o[d] = (__bf16)(x1 * c - x2 * sn);
    o[d + 64] = (__bf16)(x2 * c + x1 * sn);
}

// ---------------- flash attention v4 (pipelined, causal, GQA, fixed-max softmax) ----------------
// grid (NH, 16): t = ty<8 ? ty : 23-ty (complementary causal walls per CU).
// 4 waves x 32 q-rows (128-row q-tile), 64-key k-tiles, nk = 2t+2.
// Pipeline per iter: stage V(kt) -> QK(kt)+softmax -> barrier (drains V) ->
// stage K(kt+1) -> PV(kt) -> barrier (drains K). Every async batch gets a full
// MFMA phase of latency cover before its drain. (v5 single-barrier variant
// measured ~15 us WORSE -- reverted and kept v4.)
__global__ __launch_bounds__(256, 2) void flash_attn(const __bf16* __restrict__ Q,
                                                     const __bf16* __restrict__ Kb,
                                                     const __bf16* __restrict__ Vt,
                                                     __bf16* __restrict__ O) {
    __shared__ __bf16 k_lds[2][64 * 128];  // [key][dim], XOR-swizzled chunks, double-buffered
    __shared__ __bf16 vt_lds[128 * 64];    // [dim][key], XOR-swizzled chunks
    __shared__ __bf16 p_lds[128 * 72];     // P C-layout -> A-layout round trip

    const int tid = threadIdx.x;
    const int wave = tid >> 6, lane = tid & 63;
    const int quad = lane >> 4, l16 = lane & 15;
    const int h = blockIdx.x;
    const int ty = blockIdx.y;
    const int t = (ty < 8) ? ty : 23 - ty;
    const int qb0 = t * 128;
    const int wrow = wave * 32;
    const int kvh = h >> 3;
    const float sl2e = 0.12752039149672056f;  // (1/sqrt(128)) * log2(e)

    // Q fragments in registers (A-layout), loaded once
    bf16x8 qfr[2][4];
#pragma unroll
    for (int mi = 0; mi < 2; mi++)
#pragma unroll
        for (int kk = 0; kk < 4; kk++)
            qfr[mi][kk] = *(const bf16x8*)(Q + (size_t)(qb0 + wrow + mi * 16 + l16) * D_MODEL
                                           + h * HD + kk * 32 + quad * 8);

    f32x4 acc[2][8];
#pragma unroll
    for (int mi = 0; mi < 2; mi++)
#pragma unroll
        for (int dt = 0; dt < 8; dt++) acc[mi][dt] = (f32x4)0.0f;
    float rs[2][4] = {{0.f, 0.f, 0.f, 0.f}, {0.f, 0.f, 0.f, 0.f}};

    const int nk = 2 * t + 2;

    // prestage K(0) into k_lds[0]
#pragma unroll
    for (int it = 0; it < 4; it++) {
        int c = tid + it * 256;
        int krow = c >> 4, kcb = c & 15;
        async16(Kb + (size_t)krow * KV_W + kvh * HD + ((kcb ^ (krow & 15)) << 3),
                k_lds[0] + c * 8);
    }
    __syncthreads();   // publish K(0)

    for (int kt = 0; kt < nk; kt++) {
        const int k0 = kt * 64;
        const int cur = kt & 1;

        // stage V(kt) (overlaps QK compute below; vbuf reads from iter kt-1
        // completed before the previous iteration's second barrier)
#pragma unroll
        for (int it = 0; it < 4; it++) {
            int c = tid + it * 256;
            int vrow = c >> 3, vcb = c & 7;
            async16(Vt + (size_t)(kvh * HD + vrow) * S_LEN + k0 + ((vcb ^ (vrow & 7)) << 3),
                    vt_lds + c * 8);
        }

        // ---- S = Q K^T from k_lds[cur] ----
        f32x4 sc[2][4];
#pragma unroll
        for (int mi = 0; mi < 2; mi++)
#pragma unroll
            for (int j = 0; j < 4; j++) sc[mi][j] = (f32x4)0.0f;
#pragma unroll
        for (int j = 0; j < 4; j++)
#pragma unroll
            for (int kk = 0; kk < 4; kk++) {
                bf16x8 kf = *(const bf16x8*)(k_lds[cur] + (((j * 16 + l16) << 4) + ((kk * 4 + quad) ^ l16)) * 8);
                sc[0][j] = __builtin_amdgcn_mfma_f32_16x16x32_bf16(qfr[0][kk], kf, sc[0][j], 0, 0, 0);
                sc[1][j] = __builtin_amdgcn_mfma_f32_16x16x32_bf16(qfr[1][kk], kf, sc[1][j], 0, 0, 0);
            }

        // ---- fixed-max softmax: p = exp2(s*scale*log2e), masked -> 0 ----
        const bool hasmask = (kt >= 2 * t);
#pragma unroll
        for (int mi = 0; mi < 2; mi++) {
            int rowb = qb0 + wrow + mi * 16 + quad * 4;
#pragma unroll
            for (int j = 0; j < 4; j++) {
                int kg = k0 + j * 16 + l16;
#pragma unroll
                for (int r = 0; r < 4; r++) {
                    float p = __builtin_amdgcn_exp2f(sc[mi][j][r] * sl2e);
                    if (hasmask && kg > rowb + r) p = 0.0f;
                    rs[mi][r] += p;
                    p_lds[(wrow + mi * 16 + quad * 4 + r) * 72 + j * 16 + l16] = (__bf16)p;
                }
            }
        }

        __syncthreads();   // drains V(kt) (cover: QK phase); all QK reads of k_lds[cur] done

        // stage K(kt+1) into the other buffer (overlaps PV compute; k_lds[cur^1]
        // reads finished at iter kt-1 before a barrier)
        if (kt + 1 < nk) {
#pragma unroll
            for (int it = 0; it < 4; it++) {
                int c = tid + it * 256;
                int krow = c >> 4, kcb = c & 15;
                async16(Kb + (size_t)(k0 + 64 + krow) * KV_W + kvh * HD + ((kcb ^ (krow & 15)) << 3),
                        k_lds[cur ^ 1] + c * 8);
            }
        }

        // ---- O += P V (p_lds rows wave-private; lgkmcnt orders within wave) ----
        bf16x8 pf[2][2];
#pragma unroll
        for (int mi = 0; mi < 2; mi++)
#pragma unroll
            for (int kk = 0; kk < 2; kk++)
                pf[mi][kk] = *(const bf16x8*)(p_lds + (wrow + mi * 16 + l16) * 72 + kk * 32 + quad * 8);
#pragma unroll
        for (int dt = 0; dt < 8; dt++)
#pragma unroll
            for (int kk = 0; kk < 2; kk++) {
                bf16x8 vf = *(const bf16x8*)(vt_lds + (((dt * 16 + l16) << 3) + ((kk * 4 + quad) ^ (l16 & 7))) * 8);
                acc[0][dt] = __builtin_amdgcn_mfma_f32_16x16x32_bf16(pf[0][kk], vf, acc[0][dt], 0, 0, 0);
                acc[1][dt] = __builtin_amdgcn_mfma_f32_16x16x32_bf16(pf[1][kk], vf, acc[1][dt], 0, 0, 0);
            }

        __syncthreads();   // drains K(kt+1) (cover: PV phase); PV reads of vt_lds done
    }

    // ---- final row-sum reduction across l16 (once per block) ----
    float inv_l[2][4];
#pragma unroll
    for (int mi = 0; mi < 2; mi++)
#pragma unroll
        for (int r = 0; r < 4; r++) {
            float s = rs[mi][r];
#pragma unroll
            for (int m = 1; m <= 8; m <<= 1) s += __shfl_xor(s, m, 64);
            inv_l[mi][r] = 1.0f / s;
        }

#pragma unroll
    for (int mi = 0; mi < 2; mi++)
#pragma unroll
        for (int dt = 0; dt < 8; dt++)
#pragma unroll
            for (int r = 0; r < 4; r++) {
                int row = qb0 + wrow + mi * 16 + quad * 4 + r;
                int col = h * HD + dt * 16 + l16;
                O[(size_t)row * D_MODEL + col] = (__bf16)(acc[mi][dt][r] * inv_l[mi][r]);
            }
}

// ---------------- host launch ----------------
extern "C" void kernel_launch(void* const* d_in, const int* in_sizes, int n_in,
                              void* d_out, int out_size, void* d_ws, size_t ws_size,
                              hipStream_t stream) {
    const float* x = (const float*)d_in[0];
    const float* wq = (const float*)d_in[1];
    const float* wk = (const float*)d_in[2];
    const float* wv = (const float*)d_in[3];
    const float* wo = (const float*)d_in[4];
    float* out = (float*)d_out;

    char* ws = (char*)d_ws;
    size_t off = 0;
    auto alloc = [&](size_t bytes) {
        void* p = ws + off;
        off += (bytes + 255) & ~(size_t)255;
        return p;
    };
    __bf16* xb    = (__bf16*)alloc((size_t)S_LEN * D_MODEL * 2);
    __bf16* wqkvT = (__bf16*)alloc((size_t)QKV_W * D_MODEL * 2);  // [wq^T; wk^T; wv^T]
    __bf16* woT   = (__bf16*)alloc((size_t)D_MODEL * D_MODEL * 2);
    __bf16* qkb   = (__bf16*)alloc((size_t)S_LEN * QK_W * 2);     // pre-rope q|k
    __bf16* vtb   = (__bf16*)alloc((size_t)KV_W * S_LEN * 2);     // V^T
    __bf16* qb    = (__bf16*)alloc((size_t)S_LEN * D_MODEL * 2);  // post-rope Q
    __bf16* kb    = (__bf16*)alloc((size_t)S_LEN * KV_W * 2);     // post-rope K
    __bf16* ob    = (__bf16*)alloc((size_t)S_LEN * D_MODEL * 2);  // attention out

    // 1. casts / transposes
    cast_f32_bf16<<<(S_LEN * D_MODEL) / (256 * 4), 256, 0, stream>>>(x, xb, S_LEN * D_MODEL);
    transpose_cast<<<dim3(D_MODEL / 64, D_MODEL / 64), 256, 0, stream>>>(wq, wqkvT, D_MODEL, D_MODEL);
    transpose_cast<<<dim3(KV_W / 64, D_MODEL / 64), 256, 0, stream>>>(wk, wqkvT + (size_t)D_MODEL * D_MODEL, D_MODEL, KV_W);
    transpose_cast<<<dim3(KV_W / 64, D_MODEL / 64), 256, 0, stream>>>(wv, wqkvT + (size_t)QK_W * D_MODEL, D_MODEL, KV_W);
    transpose_cast<<<dim3(D_MODEL / 64, D_MODEL / 64), 256, 0, stream>>>(wo, woT, D_MODEL, D_MODEL);

    // 2. fused Q+K+V projection (bf16 out; V written transposed) -- 640 blocks
    gemm_bf16<1><<<dim3(QKV_W / 128, S_LEN / 128), 256, 0, stream>>>(xb, wqkvT, qkb, vtb, S_LEN, QKV_W, D_MODEL);

    // 3. RoPE
    rope_cast<<<(S_LEN * NH * 64) / 256, 256, 0, stream>>>(qkb, QK_W, 0, qb, D_MODEL, NH, S_LEN * NH * 64);
    rope_cast<<<(S_LEN * NKV * 64) / 256, 256, 0, stream>>>(qkb, QK_W, D_MODEL, kb, KV_W, NKV, S_LEN * NKV * 64);

    // 4. attention (512 blocks, 2/CU, complementary-tile swizzle)
    flash_attn<<<dim3(NH, 16), 256, 0, stream>>>(qb, kb, vtb, ob);

    // 5. output projection -> fp32 d_out -- 512 blocks
    gemm_bf16<0><<<dim3(D_MODEL / 128, S_LEN / 128), 256, 0, stream>>>(ob, woT, out, nullptr, S_LEN, D_MODEL, D_MODEL);
}